// Round 3
// baseline (78.473 us; speedup 1.0000x reference)
//
#include <hip/hip_runtime.h>
#include <math.h>

#define SMALL_EPS 1e-8f

__device__ __forceinline__ float frcp(float x) { return __builtin_amdgcn_rcpf(x); }
__device__ __forceinline__ float frsq(float x) { return __builtin_amdgcn_rsqf(x); }
__device__ __forceinline__ float ldnt(const float* p) { return __builtin_nontemporal_load(p); }
__device__ __forceinline__ int   ldnti(const int* p)  { return __builtin_nontemporal_load(p); }

// max abs err ~7e-5 rad (Abramowitz-Stegun 4.4.45)
__device__ __forceinline__ float fast_acos(float x) {
    float ax = fabsf(x);
    float r = sqrtf(fmaxf(1.0f - ax, 0.0f)) *
        (1.5707288f + ax * (-0.2121144f + ax * (0.0742610f + ax * (-0.0187293f))));
    return (x < 0.0f) ? (3.14159265358979f - r) : r;
}

// exp map to (unit quaternion, translation):  xi[6] -> q[4], t[3]
__device__ __forceinline__ void exp_se3_quat(const float xi[6], float q[4], float t[3]) {
    const float x = xi[0], y = xi[1], z = xi[2];
    const float t2 = x * x + y * y + z * z;
    const float t2s = fmaxf(t2, 1e-12f);
    const float rth = frsq(t2s);          // 1/sqrt
    const float th  = t2s * rth;          // sqrt
    const float rt2 = rth * rth;          // 1/t2s
    float sh, ch;
    __sincosf(0.5f * th, &sh, &ch);
    const bool small = t2 < SMALL_EPS;
    const float k = small ? 0.5f - t2 * (1.0f / 48.0f) : sh * rth;  // sin(th/2)/th
    q[0] = ch; q[1] = k * x; q[2] = k * y; q[3] = k * z;
    const float sin_th = 2.0f * sh * ch;
    const float cos_th = 1.0f - 2.0f * sh * sh;
    const float B = small ? 0.5f - t2 * (1.0f / 24.0f)            : (1.0f - cos_th) * rt2;
    const float C = small ? (1.0f / 6.0f) - t2 * (1.0f / 120.0f)  : (th - sin_th) * rt2 * rth;
    const float v0 = xi[3], v1 = xi[4], v2 = xi[5];
    // c = w x v ; d = w x c ;  t = v + B*c + C*d   (V = I + B W + C W^2)
    const float c0 = y * v2 - z * v1;
    const float c1 = z * v0 - x * v2;
    const float c2 = x * v1 - y * v0;
    const float d0 = y * c2 - z * c1;
    const float d1 = z * c0 - x * c2;
    const float d2 = x * c1 - y * c0;
    t[0] = v0 + B * c0 + C * d0;
    t[1] = v1 + B * c1 + C * d1;
    t[2] = v2 + B * c2 + C * d2;
}

// o = conj(a) * b   (quaternion product; equals R(a)^T R(b))
__device__ __forceinline__ void qconj_mul(const float a[4], const float b[4], float o[4]) {
    o[0] = a[0] * b[0] + a[1] * b[1] + a[2] * b[2] + a[3] * b[3];
    o[1] = a[0] * b[1] - b[0] * a[1] - (a[2] * b[3] - a[3] * b[2]);
    o[2] = a[0] * b[2] - b[0] * a[2] - (a[3] * b[1] - a[1] * b[3]);
    o[3] = a[0] * b[3] - b[0] * a[3] - (a[1] * b[2] - a[2] * b[1]);
}

// o = R(q)^T v  (rotate v by conjugate of q)
__device__ __forceinline__ void qconj_rot(const float q[4], const float v[3], float o[3]) {
    const float ux = -q[1], uy = -q[2], uz = -q[3];
    const float tx = 2.0f * (uy * v[2] - uz * v[1]);
    const float ty = 2.0f * (uz * v[0] - ux * v[2]);
    const float tz = 2.0f * (ux * v[1] - uy * v[0]);
    o[0] = v[0] + q[0] * tx + (uy * tz - uz * ty);
    o[1] = v[1] + q[0] * ty + (uz * tx - ux * tz);
    o[2] = v[2] + q[0] * tz + (ux * ty - uy * tx);
}

// log map from (q, t) -> sum of squares of xi
// tr(R) = 4 qw^2 - 1 ;  (R21-R12, R02-R20, R10-R01) = 4 qw * q.xyz
__device__ __forceinline__ float log_se3_sq_quat(const float q[4], const float t[3]) {
    const float cth = fminf(fmaxf(2.0f * q[0] * q[0] - 1.0f, -1.0f), 1.0f);
    const float th = fast_acos(cth);
    const float t2 = th * th;
    const float t2s = fmaxf(t2, 1e-12f);
    const float rt2s = frcp(t2s);
    const bool small = t2 < SMALL_EPS;
    const float sth = sqrtf(fmaxf(1.0f - cth * cth, 0.0f));  // sin(acos(x))
    const float fac = small ? 0.5f + t2 * (1.0f / 12.0f) : 0.5f * th * frcp(sth);
    const float g = 4.0f * q[0] * fac;
    const float wx = g * q[1], wy = g * q[2], wz = g * q[3];
    const float A = small ? 1.0f : sth * frcp(th);
    const float B = small ? 0.5f : (1.0f - cth) * rt2s;
    const float coef = small ? (1.0f / 12.0f) + t2 * (1.0f / 720.0f)
                             : (1.0f - 0.5f * A * frcp(B)) * rt2s;
    // Vinv t = t - 0.5 (w x t) + coef (w x (w x t))
    const float c0 = wy * t[2] - wz * t[1];
    const float c1 = wz * t[0] - wx * t[2];
    const float c2 = wx * t[1] - wy * t[0];
    const float d0 = wy * c2 - wz * c1;
    const float d1 = wz * c0 - wx * c2;
    const float d2 = wx * c1 - wy * c0;
    const float vx = t[0] - 0.5f * c0 + coef * d0;
    const float vy = t[1] - 0.5f * c1 + coef * d1;
    const float vz = t[2] - 0.5f * c2 + coef * d2;
    return wx * wx + wy * wy + wz * wz + vx * vx + vy * vy + vz * vz;
}

__device__ __forceinline__ void load6(const float* __restrict__ p, float xi[6]) {
    const float2* p2 = reinterpret_cast<const float2*>(p);
    float2 a = p2[0], b = p2[1], c = p2[2];
    xi[0] = a.x; xi[1] = a.y; xi[2] = b.x; xi[3] = b.y; xi[4] = c.x; xi[5] = c.y;
}

__device__ __forceinline__ void load6_nt(const float* __restrict__ p, float xi[6]) {
    #pragma unroll
    for (int k = 0; k < 6; ++k) xi[k] = ldnt(p + k);
}

// ---------- kernel 1: exp all poses into 32B (quat+t) records ----------
__global__ __launch_bounds__(256) void exp_poses_kernel(
    const float* __restrict__ poses, float* __restrict__ table, int N)
{
    const int i = blockIdx.x * blockDim.x + threadIdx.x;
    if (i >= N) return;
    float xi[6];
    load6(poses + 6 * (size_t)i, xi);
    float q[4], t[3];
    exp_se3_quat(xi, q, t);
    float4* slot = reinterpret_cast<float4*>(table + 8 * (size_t)i);
    slot[0] = make_float4(q[0], q[1], q[2], q[3]);
    slot[1] = make_float4(t[0], t[1], t[2], 0.0f);
}

__device__ __forceinline__ void load_pose(const float* __restrict__ table, int i,
                                          float q[4], float t[3])
{
    const float4* slot = reinterpret_cast<const float4*>(table + 8 * (size_t)i);
    const float4 a = slot[0], b = slot[1];
    q[0] = a.x; q[1] = a.y; q[2] = a.z; q[3] = a.w;
    t[0] = b.x; t[1] = b.y; t[2] = b.z;
}

// ---------- kernel 2: per-edge residual, block partial sums ----------
__global__ __launch_bounds__(256) void edge_loss_kernel(
    const float* __restrict__ table,
    const int* __restrict__ edges,
    const float* __restrict__ meas,
    float* __restrict__ partials,
    int N, int E)
{
    const int e = blockIdx.x * blockDim.x + threadIdx.x;
    float loss = 0.0f;
    if (e < E) {
        int i = ldnti(edges + 2 * e);
        int j = ldnti(edges + 2 * e + 1);
        i = min(max(i, 0), N - 1);
        j = min(max(j, 0), N - 1);

        float qi[4], ti[3], qj[4], tj[3];
        load_pose(table, i, qi, ti);
        load_pose(table, j, qj, tj);

        float xi_m[6];
        load6_nt(meas + 6 * (size_t)e, xi_m);
        float qm[4], tm[3];
        exp_se3_quat(xi_m, qm, tm);

        // qc = conj(qi) qj ; tc = R(qi)^T (tj - ti)
        float qc[4], tc[3];
        const float dvec[3] = { tj[0] - ti[0], tj[1] - ti[1], tj[2] - ti[2] };
        qconj_mul(qi, qj, qc);
        qconj_rot(qi, dvec, tc);

        // qr = conj(qm) qc ; tr = R(qm)^T (tc - tm)
        float qr[4], tr[3];
        const float evec[3] = { tc[0] - tm[0], tc[1] - tm[1], tc[2] - tm[2] };
        qconj_mul(qm, qc, qr);
        qconj_rot(qm, evec, tr);

        loss = log_se3_sq_quat(qr, tr);
    }

    #pragma unroll
    for (int off = 32; off > 0; off >>= 1)
        loss += __shfl_down(loss, off);

    __shared__ float sdata[4];
    const int lane = threadIdx.x & 63;
    const int wid = threadIdx.x >> 6;
    if (lane == 0) sdata[wid] = loss;
    __syncthreads();
    if (threadIdx.x == 0)
        partials[blockIdx.x] = (sdata[0] + sdata[1]) + (sdata[2] + sdata[3]);
}

// ---------- kernel 3: final reduce ----------
__global__ __launch_bounds__(256) void reduce_kernel(
    const float* __restrict__ partials, int n, float* __restrict__ out, float invE)
{
    float s = 0.0f;
    for (int i = threadIdx.x; i < n; i += 256) s += partials[i];
    #pragma unroll
    for (int off = 32; off > 0; off >>= 1) s += __shfl_down(s, off);
    __shared__ float sd[4];
    const int lane = threadIdx.x & 63;
    const int wid = threadIdx.x >> 6;
    if (lane == 0) sd[wid] = s;
    __syncthreads();
    if (threadIdx.x == 0) out[0] = ((sd[0] + sd[1]) + (sd[2] + sd[3])) * invE;
}

// ---------- fallback (ws too small): fused, atomic ----------
__global__ void zero_out_kernel(float* out) { out[0] = 0.0f; }

__global__ __launch_bounds__(256) void fused_kernel(
    const float* __restrict__ poses,
    const int* __restrict__ edges,
    const float* __restrict__ meas,
    float* __restrict__ out,
    int N, int E, float invE)
{
    const int e = blockIdx.x * blockDim.x + threadIdx.x;
    float loss = 0.0f;
    if (e < E) {
        int i = edges[2 * e];
        int j = edges[2 * e + 1];
        i = min(max(i, 0), N - 1);
        j = min(max(j, 0), N - 1);
        float xi_i[6], xi_j[6], xi_m[6];
        load6(poses + 6 * (size_t)i, xi_i);
        load6(poses + 6 * (size_t)j, xi_j);
        load6(meas + 6 * (size_t)e, xi_m);
        float qi[4], ti[3], qj[4], tj[3], qm[4], tm[3];
        exp_se3_quat(xi_i, qi, ti);
        exp_se3_quat(xi_j, qj, tj);
        exp_se3_quat(xi_m, qm, tm);
        float qc[4], tc[3];
        const float dvec[3] = { tj[0] - ti[0], tj[1] - ti[1], tj[2] - ti[2] };
        qconj_mul(qi, qj, qc);
        qconj_rot(qi, dvec, tc);
        float qr[4], tr[3];
        const float evec[3] = { tc[0] - tm[0], tc[1] - tm[1], tc[2] - tm[2] };
        qconj_mul(qm, qc, qr);
        qconj_rot(qm, evec, tr);
        loss = log_se3_sq_quat(qr, tr);
    }
    #pragma unroll
    for (int off = 32; off > 0; off >>= 1) loss += __shfl_down(loss, off);
    __shared__ float sdata[4];
    const int lane = threadIdx.x & 63;
    const int wid = threadIdx.x >> 6;
    if (lane == 0) sdata[wid] = loss;
    __syncthreads();
    if (threadIdx.x == 0)
        atomicAdd(out, ((sdata[0] + sdata[1]) + (sdata[2] + sdata[3])) * invE);
}

extern "C" void kernel_launch(void* const* d_in, const int* in_sizes, int n_in,
                              void* d_out, int out_size, void* d_ws, size_t ws_size,
                              hipStream_t stream) {
    const float* poses = (const float*)d_in[0];
    const int*   edges = (const int*)d_in[1];
    const float* meas  = (const float*)d_in[2];
    float* out = (float*)d_out;

    const int N = in_sizes[0] / 6;
    const int E = in_sizes[2] / 6;
    const float invE = 1.0f / (float)E;

    const int block = 256;
    const int grid_e = (E + block - 1) / block;
    const size_t table_bytes = (size_t)N * 8 * sizeof(float);       // 32 B / pose
    const size_t need = table_bytes + (size_t)grid_e * sizeof(float);

    if (ws_size >= need) {
        float* table = (float*)d_ws;
        float* partials = (float*)((char*)d_ws + table_bytes);
        const int grid_n = (N + block - 1) / block;
        exp_poses_kernel<<<grid_n, block, 0, stream>>>(poses, table, N);
        edge_loss_kernel<<<grid_e, block, 0, stream>>>(table, edges, meas, partials, N, E);
        reduce_kernel<<<1, block, 0, stream>>>(partials, grid_e, out, invE);
    } else {
        zero_out_kernel<<<1, 1, 0, stream>>>(out);
        fused_kernel<<<grid_e, block, 0, stream>>>(poses, edges, meas, out, N, E, invE);
    }
}

// Round 4
// 58.761 us; speedup vs baseline: 1.3355x; 1.3355x over previous
//
#include <hip/hip_runtime.h>
#include <math.h>

#define SMALL_EPS 1e-8f

typedef float f4 __attribute__((ext_vector_type(4)));
typedef int   i4 __attribute__((ext_vector_type(4)));

__device__ __forceinline__ float frcp(float x) { return __builtin_amdgcn_rcpf(x); }
__device__ __forceinline__ float frsq(float x) { return __builtin_amdgcn_rsqf(x); }
__device__ __forceinline__ f4 ldnt4(const float* p) {
    return __builtin_nontemporal_load(reinterpret_cast<const f4*>(p));
}
__device__ __forceinline__ i4 ldnt4i(const int* p) {
    return __builtin_nontemporal_load(reinterpret_cast<const i4*>(p));
}

// max abs err ~7e-5 rad (Abramowitz-Stegun 4.4.45)
__device__ __forceinline__ float fast_acos(float x) {
    float ax = fabsf(x);
    float r = sqrtf(fmaxf(1.0f - ax, 0.0f)) *
        (1.5707288f + ax * (-0.2121144f + ax * (0.0742610f + ax * (-0.0187293f))));
    return (x < 0.0f) ? (3.14159265358979f - r) : r;
}

// exp map to (unit quaternion, translation):  xi[6] -> q[4], t[3]
__device__ __forceinline__ void exp_se3_quat(const float xi[6], float q[4], float t[3]) {
    const float x = xi[0], y = xi[1], z = xi[2];
    const float t2 = x * x + y * y + z * z;
    const float t2s = fmaxf(t2, 1e-12f);
    const float rth = frsq(t2s);          // 1/sqrt
    const float th  = t2s * rth;          // sqrt
    const float rt2 = rth * rth;          // 1/t2s
    float sh, ch;
    __sincosf(0.5f * th, &sh, &ch);
    const bool small = t2 < SMALL_EPS;
    const float k = small ? 0.5f - t2 * (1.0f / 48.0f) : sh * rth;  // sin(th/2)/th
    q[0] = ch; q[1] = k * x; q[2] = k * y; q[3] = k * z;
    const float sin_th = 2.0f * sh * ch;
    const float cos_th = 1.0f - 2.0f * sh * sh;
    const float B = small ? 0.5f - t2 * (1.0f / 24.0f)            : (1.0f - cos_th) * rt2;
    const float C = small ? (1.0f / 6.0f) - t2 * (1.0f / 120.0f)  : (th - sin_th) * rt2 * rth;
    const float v0 = xi[3], v1 = xi[4], v2 = xi[5];
    const float c0 = y * v2 - z * v1;
    const float c1 = z * v0 - x * v2;
    const float c2 = x * v1 - y * v0;
    const float d0 = y * c2 - z * c1;
    const float d1 = z * c0 - x * c2;
    const float d2 = x * c1 - y * c0;
    t[0] = v0 + B * c0 + C * d0;
    t[1] = v1 + B * c1 + C * d1;
    t[2] = v2 + B * c2 + C * d2;
}

// o = conj(a) * b
__device__ __forceinline__ void qconj_mul(const float a[4], const float b[4], float o[4]) {
    o[0] = a[0] * b[0] + a[1] * b[1] + a[2] * b[2] + a[3] * b[3];
    o[1] = a[0] * b[1] - b[0] * a[1] - (a[2] * b[3] - a[3] * b[2]);
    o[2] = a[0] * b[2] - b[0] * a[2] - (a[3] * b[1] - a[1] * b[3]);
    o[3] = a[0] * b[3] - b[0] * a[3] - (a[1] * b[2] - a[2] * b[1]);
}

// o = R(q)^T v
__device__ __forceinline__ void qconj_rot(const float q[4], const float v[3], float o[3]) {
    const float ux = -q[1], uy = -q[2], uz = -q[3];
    const float tx = 2.0f * (uy * v[2] - uz * v[1]);
    const float ty = 2.0f * (uz * v[0] - ux * v[2]);
    const float tz = 2.0f * (ux * v[1] - uy * v[0]);
    o[0] = v[0] + q[0] * tx + (uy * tz - uz * ty);
    o[1] = v[1] + q[0] * ty + (uz * tx - ux * tz);
    o[2] = v[2] + q[0] * tz + (ux * ty - uy * tx);
}

// log map from (q, t) -> sum of squares of xi
__device__ __forceinline__ float log_se3_sq_quat(const float q[4], const float t[3]) {
    const float cth = fminf(fmaxf(2.0f * q[0] * q[0] - 1.0f, -1.0f), 1.0f);
    const float th = fast_acos(cth);
    const float t2 = th * th;
    const float t2s = fmaxf(t2, 1e-12f);
    const float rt2s = frcp(t2s);
    const bool small = t2 < SMALL_EPS;
    const float sth = sqrtf(fmaxf(1.0f - cth * cth, 0.0f));
    const float fac = small ? 0.5f + t2 * (1.0f / 12.0f) : 0.5f * th * frcp(sth);
    const float g = 4.0f * q[0] * fac;
    const float wx = g * q[1], wy = g * q[2], wz = g * q[3];
    const float A = small ? 1.0f : sth * frcp(th);
    const float B = small ? 0.5f : (1.0f - cth) * rt2s;
    const float coef = small ? (1.0f / 12.0f) + t2 * (1.0f / 720.0f)
                             : (1.0f - 0.5f * A * frcp(B)) * rt2s;
    const float c0 = wy * t[2] - wz * t[1];
    const float c1 = wz * t[0] - wx * t[2];
    const float c2 = wx * t[1] - wy * t[0];
    const float d0 = wy * c2 - wz * c1;
    const float d1 = wz * c0 - wx * c2;
    const float d2 = wx * c1 - wy * c0;
    const float vx = t[0] - 0.5f * c0 + coef * d0;
    const float vy = t[1] - 0.5f * c1 + coef * d1;
    const float vz = t[2] - 0.5f * c2 + coef * d2;
    return wx * wx + wy * wy + wz * wz + vx * vx + vy * vy + vz * vz;
}

__device__ __forceinline__ void load6(const float* __restrict__ p, float xi[6]) {
    const float2* p2 = reinterpret_cast<const float2*>(p);
    float2 a = p2[0], b = p2[1], c = p2[2];
    xi[0] = a.x; xi[1] = a.y; xi[2] = b.x; xi[3] = b.y; xi[4] = c.x; xi[5] = c.y;
}

// residual for one edge given pre-loaded poses (as quat+t) and measurement xi
__device__ __forceinline__ float edge_residual(
    const float qi[4], const float ti[3],
    const float qj[4], const float tj[3],
    const float xm[6])
{
    float qm[4], tm[3];
    exp_se3_quat(xm, qm, tm);
    float qc[4], tc[3];
    const float dvec[3] = { tj[0] - ti[0], tj[1] - ti[1], tj[2] - ti[2] };
    qconj_mul(qi, qj, qc);
    qconj_rot(qi, dvec, tc);
    float qr[4], tr[3];
    const float evec[3] = { tc[0] - tm[0], tc[1] - tm[1], tc[2] - tm[2] };
    qconj_mul(qm, qc, qr);
    qconj_rot(qm, evec, tr);
    return log_se3_sq_quat(qr, tr);
}

// ---------- kernel 1: exp all poses into 32B (quat+t) records ----------
__global__ __launch_bounds__(256) void exp_poses_kernel(
    const float* __restrict__ poses, float* __restrict__ table, int N)
{
    const int i = blockIdx.x * blockDim.x + threadIdx.x;
    if (i >= N) return;
    float xi[6];
    load6(poses + 6 * (size_t)i, xi);
    float q[4], t[3];
    exp_se3_quat(xi, q, t);
    f4* slot = reinterpret_cast<f4*>(table + 8 * (size_t)i);
    slot[0] = (f4){q[0], q[1], q[2], q[3]};
    slot[1] = (f4){t[0], t[1], t[2], 0.0f};
}

__device__ __forceinline__ void load_pose(const float* __restrict__ table, int i,
                                          float q[4], float t[3])
{
    const f4* slot = reinterpret_cast<const f4*>(table + 8 * (size_t)i);
    const f4 a = slot[0], b = slot[1];
    q[0] = a.x; q[1] = a.y; q[2] = a.z; q[3] = a.w;
    t[0] = b.x; t[1] = b.y; t[2] = b.z;
}

// ---------- kernel 2: per-edge residual, 2 edges/thread, block partials ----------
__global__ __launch_bounds__(256) void edge_loss_kernel(
    const float* __restrict__ table,
    const int* __restrict__ edges,
    const float* __restrict__ meas,
    float* __restrict__ partials,
    int N, int E)
{
    const int t = blockIdx.x * blockDim.x + threadIdx.x;
    const int e0 = 2 * t;
    float loss = 0.0f;

    if (e0 + 1 < E) {
        // both edges valid: fully vectorized load path
        const i4 ed = ldnt4i(edges + 4 * (size_t)t);
        const int i0 = min(max(ed.x, 0), N - 1);
        const int j0 = min(max(ed.y, 0), N - 1);
        const int i1 = min(max(ed.z, 0), N - 1);
        const int j1 = min(max(ed.w, 0), N - 1);

        // issue all 4 pose gathers (8x16B) before any compute
        float qi0[4], ti0[3], qj0[4], tj0[3];
        float qi1[4], ti1[3], qj1[4], tj1[3];
        load_pose(table, i0, qi0, ti0);
        load_pose(table, j0, qj0, tj0);
        load_pose(table, i1, qi1, ti1);
        load_pose(table, j1, qj1, tj1);

        // both measurements: 3x float4, 16B-aligned (48B per thread)
        const float* mp = meas + 12 * (size_t)t;
        const f4 m0 = ldnt4(mp);
        const f4 m1 = ldnt4(mp + 4);
        const f4 m2 = ldnt4(mp + 8);
        const float xmA[6] = { m0.x, m0.y, m0.z, m0.w, m1.x, m1.y };
        const float xmB[6] = { m1.z, m1.w, m2.x, m2.y, m2.z, m2.w };

        loss = edge_residual(qi0, ti0, qj0, tj0, xmA)
             + edge_residual(qi1, ti1, qj1, tj1, xmB);
    } else if (e0 < E) {
        // tail: single edge, scalar-safe loads
        int i = edges[2 * e0];
        int j = edges[2 * e0 + 1];
        i = min(max(i, 0), N - 1);
        j = min(max(j, 0), N - 1);
        float qi[4], ti[3], qj[4], tj[3];
        load_pose(table, i, qi, ti);
        load_pose(table, j, qj, tj);
        float xm[6];
        load6(meas + 6 * (size_t)e0, xm);
        loss = edge_residual(qi, ti, qj, tj, xm);
    }

    #pragma unroll
    for (int off = 32; off > 0; off >>= 1)
        loss += __shfl_down(loss, off);

    __shared__ float sdata[4];
    const int lane = threadIdx.x & 63;
    const int wid = threadIdx.x >> 6;
    if (lane == 0) sdata[wid] = loss;
    __syncthreads();
    if (threadIdx.x == 0)
        partials[blockIdx.x] = (sdata[0] + sdata[1]) + (sdata[2] + sdata[3]);
}

// ---------- kernel 3: final reduce ----------
__global__ __launch_bounds__(256) void reduce_kernel(
    const float* __restrict__ partials, int n, float* __restrict__ out, float invE)
{
    float s = 0.0f;
    for (int i = threadIdx.x; i < n; i += 256) s += partials[i];
    #pragma unroll
    for (int off = 32; off > 0; off >>= 1) s += __shfl_down(s, off);
    __shared__ float sd[4];
    const int lane = threadIdx.x & 63;
    const int wid = threadIdx.x >> 6;
    if (lane == 0) sd[wid] = s;
    __syncthreads();
    if (threadIdx.x == 0) out[0] = ((sd[0] + sd[1]) + (sd[2] + sd[3])) * invE;
}

// ---------- fallback (ws too small): fused, atomic ----------
__global__ void zero_out_kernel(float* out) { out[0] = 0.0f; }

__global__ __launch_bounds__(256) void fused_kernel(
    const float* __restrict__ poses,
    const int* __restrict__ edges,
    const float* __restrict__ meas,
    float* __restrict__ out,
    int N, int E, float invE)
{
    const int e = blockIdx.x * blockDim.x + threadIdx.x;
    float loss = 0.0f;
    if (e < E) {
        int i = edges[2 * e];
        int j = edges[2 * e + 1];
        i = min(max(i, 0), N - 1);
        j = min(max(j, 0), N - 1);
        float xi_i[6], xi_j[6], xi_m[6];
        load6(poses + 6 * (size_t)i, xi_i);
        load6(poses + 6 * (size_t)j, xi_j);
        load6(meas + 6 * (size_t)e, xi_m);
        float qi[4], ti[3], qj[4], tj[3];
        exp_se3_quat(xi_i, qi, ti);
        exp_se3_quat(xi_j, qj, tj);
        loss = edge_residual(qi, ti, qj, tj, xi_m);
    }
    #pragma unroll
    for (int off = 32; off > 0; off >>= 1) loss += __shfl_down(loss, off);
    __shared__ float sdata[4];
    const int lane = threadIdx.x & 63;
    const int wid = threadIdx.x >> 6;
    if (lane == 0) sdata[wid] = loss;
    __syncthreads();
    if (threadIdx.x == 0)
        atomicAdd(out, ((sdata[0] + sdata[1]) + (sdata[2] + sdata[3])) * invE);
}

extern "C" void kernel_launch(void* const* d_in, const int* in_sizes, int n_in,
                              void* d_out, int out_size, void* d_ws, size_t ws_size,
                              hipStream_t stream) {
    const float* poses = (const float*)d_in[0];
    const int*   edges = (const int*)d_in[1];
    const float* meas  = (const float*)d_in[2];
    float* out = (float*)d_out;

    const int N = in_sizes[0] / 6;
    const int E = in_sizes[2] / 6;
    const float invE = 1.0f / (float)E;

    const int block = 256;
    const int nthreads = (E + 1) / 2;                 // 2 edges per thread
    const int grid_e = (nthreads + block - 1) / block;
    const size_t table_bytes = (size_t)N * 8 * sizeof(float);   // 32 B / pose
    const size_t need = table_bytes + (size_t)grid_e * sizeof(float);

    if (ws_size >= need) {
        float* table = (float*)d_ws;
        float* partials = (float*)((char*)d_ws + table_bytes);
        const int grid_n = (N + block - 1) / block;
        exp_poses_kernel<<<grid_n, block, 0, stream>>>(poses, table, N);
        edge_loss_kernel<<<grid_e, block, 0, stream>>>(table, edges, meas, partials, N, E);
        reduce_kernel<<<1, block, 0, stream>>>(partials, grid_e, out, invE);
    } else {
        zero_out_kernel<<<1, 1, 0, stream>>>(out);
        const int grid_f = (E + block - 1) / block;
        fused_kernel<<<grid_f, block, 0, stream>>>(poses, edges, meas, out, N, E, invE);
    }
}

// Round 5
// 58.202 us; speedup vs baseline: 1.3483x; 1.0096x over previous
//
#include <hip/hip_runtime.h>
#include <math.h>

#define SMALL_EPS 1e-8f

typedef float f4 __attribute__((ext_vector_type(4)));
typedef int   i4 __attribute__((ext_vector_type(4)));

__device__ __forceinline__ float frcp(float x) { return __builtin_amdgcn_rcpf(x); }
__device__ __forceinline__ float frsq(float x) { return __builtin_amdgcn_rsqf(x); }
__device__ __forceinline__ f4 ldnt4(const float* p) {
    return __builtin_nontemporal_load(reinterpret_cast<const f4*>(p));
}
__device__ __forceinline__ i4 ldnt4i(const int* p) {
    return __builtin_nontemporal_load(reinterpret_cast<const i4*>(p));
}

// max abs err ~7e-5 rad (Abramowitz-Stegun 4.4.45)
__device__ __forceinline__ float fast_acos(float x) {
    float ax = fabsf(x);
    float r = sqrtf(fmaxf(1.0f - ax, 0.0f)) *
        (1.5707288f + ax * (-0.2121144f + ax * (0.0742610f + ax * (-0.0187293f))));
    return (x < 0.0f) ? (3.14159265358979f - r) : r;
}

// exp map to (unit quaternion, translation):  xi[6] -> q[4], t[3]
__device__ __forceinline__ void exp_se3_quat(const float xi[6], float q[4], float t[3]) {
    const float x = xi[0], y = xi[1], z = xi[2];
    const float t2 = x * x + y * y + z * z;
    const float t2s = fmaxf(t2, 1e-12f);
    const float rth = frsq(t2s);          // 1/sqrt
    const float th  = t2s * rth;          // sqrt
    const float rt2 = rth * rth;          // 1/t2s
    float sh, ch;
    __sincosf(0.5f * th, &sh, &ch);
    const bool small = t2 < SMALL_EPS;
    const float k = small ? 0.5f - t2 * (1.0f / 48.0f) : sh * rth;  // sin(th/2)/th
    q[0] = ch; q[1] = k * x; q[2] = k * y; q[3] = k * z;
    const float sin_th = 2.0f * sh * ch;
    const float cos_th = 1.0f - 2.0f * sh * sh;
    const float B = small ? 0.5f - t2 * (1.0f / 24.0f)            : (1.0f - cos_th) * rt2;
    const float C = small ? (1.0f / 6.0f) - t2 * (1.0f / 120.0f)  : (th - sin_th) * rt2 * rth;
    const float v0 = xi[3], v1 = xi[4], v2 = xi[5];
    const float c0 = y * v2 - z * v1;
    const float c1 = z * v0 - x * v2;
    const float c2 = x * v1 - y * v0;
    const float d0 = y * c2 - z * c1;
    const float d1 = z * c0 - x * c2;
    const float d2 = x * c1 - y * c0;
    t[0] = v0 + B * c0 + C * d0;
    t[1] = v1 + B * c1 + C * d1;
    t[2] = v2 + B * c2 + C * d2;
}

// o = conj(a) * b
__device__ __forceinline__ void qconj_mul(const float a[4], const float b[4], float o[4]) {
    o[0] = a[0] * b[0] + a[1] * b[1] + a[2] * b[2] + a[3] * b[3];
    o[1] = a[0] * b[1] - b[0] * a[1] - (a[2] * b[3] - a[3] * b[2]);
    o[2] = a[0] * b[2] - b[0] * a[2] - (a[3] * b[1] - a[1] * b[3]);
    o[3] = a[0] * b[3] - b[0] * a[3] - (a[1] * b[2] - a[2] * b[1]);
}

// o = R(q)^T v
__device__ __forceinline__ void qconj_rot(const float q[4], const float v[3], float o[3]) {
    const float ux = -q[1], uy = -q[2], uz = -q[3];
    const float tx = 2.0f * (uy * v[2] - uz * v[1]);
    const float ty = 2.0f * (uz * v[0] - ux * v[2]);
    const float tz = 2.0f * (ux * v[1] - uy * v[0]);
    o[0] = v[0] + q[0] * tx + (uy * tz - uz * ty);
    o[1] = v[1] + q[0] * ty + (uz * tx - ux * tz);
    o[2] = v[2] + q[0] * tz + (ux * ty - uy * tx);
}

// log map from (q, t) -> sum of squares of xi
__device__ __forceinline__ float log_se3_sq_quat(const float q[4], const float t[3]) {
    const float cth = fminf(fmaxf(2.0f * q[0] * q[0] - 1.0f, -1.0f), 1.0f);
    const float th = fast_acos(cth);
    const float t2 = th * th;
    const float t2s = fmaxf(t2, 1e-12f);
    const float rt2s = frcp(t2s);
    const bool small = t2 < SMALL_EPS;
    const float sth = sqrtf(fmaxf(1.0f - cth * cth, 0.0f));
    const float fac = small ? 0.5f + t2 * (1.0f / 12.0f) : 0.5f * th * frcp(sth);
    const float g = 4.0f * q[0] * fac;
    const float wx = g * q[1], wy = g * q[2], wz = g * q[3];
    const float A = small ? 1.0f : sth * frcp(th);
    const float B = small ? 0.5f : (1.0f - cth) * rt2s;
    const float coef = small ? (1.0f / 12.0f) + t2 * (1.0f / 720.0f)
                             : (1.0f - 0.5f * A * frcp(B)) * rt2s;
    const float c0 = wy * t[2] - wz * t[1];
    const float c1 = wz * t[0] - wx * t[2];
    const float c2 = wx * t[1] - wy * t[0];
    const float d0 = wy * c2 - wz * c1;
    const float d1 = wz * c0 - wx * c2;
    const float d2 = wx * c1 - wy * c0;
    const float vx = t[0] - 0.5f * c0 + coef * d0;
    const float vy = t[1] - 0.5f * c1 + coef * d1;
    const float vz = t[2] - 0.5f * c2 + coef * d2;
    return wx * wx + wy * wy + wz * wz + vx * vx + vy * vy + vz * vz;
}

__device__ __forceinline__ void load6(const float* __restrict__ p, float xi[6]) {
    const float2* p2 = reinterpret_cast<const float2*>(p);
    float2 a = p2[0], b = p2[1], c = p2[2];
    xi[0] = a.x; xi[1] = a.y; xi[2] = b.x; xi[3] = b.y; xi[4] = c.x; xi[5] = c.y;
}

// residual for one edge given pre-loaded poses (as quat+t) and measurement xi
__device__ __forceinline__ float edge_residual(
    const float qi[4], const float ti[3],
    const float qj[4], const float tj[3],
    const float xm[6])
{
    float qm[4], tm[3];
    exp_se3_quat(xm, qm, tm);
    float qc[4], tc[3];
    const float dvec[3] = { tj[0] - ti[0], tj[1] - ti[1], tj[2] - ti[2] };
    qconj_mul(qi, qj, qc);
    qconj_rot(qi, dvec, tc);
    float qr[4], tr[3];
    const float evec[3] = { tc[0] - tm[0], tc[1] - tm[1], tc[2] - tm[2] };
    qconj_mul(qm, qc, qr);
    qconj_rot(qm, evec, tr);
    return log_se3_sq_quat(qr, tr);
}

// ---------- kernel 1: exp all poses into 32B (quat+t) records ----------
__global__ __launch_bounds__(256) void exp_poses_kernel(
    const float* __restrict__ poses, float* __restrict__ table, int N)
{
    const int i = blockIdx.x * blockDim.x + threadIdx.x;
    if (i >= N) return;
    float xi[6];
    load6(poses + 6 * (size_t)i, xi);
    float q[4], t[3];
    exp_se3_quat(xi, q, t);
    f4* slot = reinterpret_cast<f4*>(table + 8 * (size_t)i);
    slot[0] = (f4){q[0], q[1], q[2], q[3]};
    slot[1] = (f4){t[0], t[1], t[2], 0.0f};
}

__device__ __forceinline__ void load_pose(const float* __restrict__ table, int i,
                                          float q[4], float t[3])
{
    const f4* slot = reinterpret_cast<const f4*>(table + 8 * (size_t)i);
    const f4 a = slot[0], b = slot[1];
    q[0] = a.x; q[1] = a.y; q[2] = a.z; q[3] = a.w;
    t[0] = b.x; t[1] = b.y; t[2] = b.z;
}

// ---------- kernel 2: per-edge residual, 4 edges/thread, block partials ----------
__global__ __launch_bounds__(256) void edge_loss_kernel(
    const float* __restrict__ table,
    const int* __restrict__ edges,
    const float* __restrict__ meas,
    float* __restrict__ partials,
    int N, int E)
{
    const int t = blockIdx.x * blockDim.x + threadIdx.x;
    const long e0 = 4L * t;
    float loss = 0.0f;

    if (e0 + 3 < E) {
        // 2 independent edge-index loads (32 B, coalesced)
        const i4 edA = ldnt4i(edges + 8 * (size_t)t);
        const i4 edB = ldnt4i(edges + 8 * (size_t)t + 4);

        // 8 independent pose gathers (2x16 B each), all issued before compute
        float qp[8][4], tp[8][3];
        load_pose(table, edA.x, qp[0], tp[0]);
        load_pose(table, edA.y, qp[1], tp[1]);
        load_pose(table, edA.z, qp[2], tp[2]);
        load_pose(table, edA.w, qp[3], tp[3]);
        load_pose(table, edB.x, qp[4], tp[4]);
        load_pose(table, edB.y, qp[5], tp[5]);
        load_pose(table, edB.z, qp[6], tp[6]);
        load_pose(table, edB.w, qp[7], tp[7]);

        // 4 measurements: 6x float4 (96 B, 16B-aligned, coalesced)
        const float* mp = meas + 24 * (size_t)t;
        const f4 m0 = ldnt4(mp);
        const f4 m1 = ldnt4(mp + 4);
        const f4 m2 = ldnt4(mp + 8);
        const f4 m3 = ldnt4(mp + 12);
        const f4 m4 = ldnt4(mp + 16);
        const f4 m5 = ldnt4(mp + 20);
        const float xm0[6] = { m0.x, m0.y, m0.z, m0.w, m1.x, m1.y };
        const float xm1[6] = { m1.z, m1.w, m2.x, m2.y, m2.z, m2.w };
        const float xm2[6] = { m3.x, m3.y, m3.z, m3.w, m4.x, m4.y };
        const float xm3[6] = { m4.z, m4.w, m5.x, m5.y, m5.z, m5.w };

        loss = edge_residual(qp[0], tp[0], qp[1], tp[1], xm0)
             + edge_residual(qp[2], tp[2], qp[3], tp[3], xm1)
             + edge_residual(qp[4], tp[4], qp[5], tp[5], xm2)
             + edge_residual(qp[6], tp[6], qp[7], tp[7], xm3);
    } else if (e0 < E) {
        // tail: scalar-safe loop (only last thread, and only if E % 4 != 0)
        for (long e = e0; e < E; ++e) {
            const int i = edges[2 * e];
            const int j = edges[2 * e + 1];
            float qi[4], ti[3], qj[4], tj[3];
            load_pose(table, i, qi, ti);
            load_pose(table, j, qj, tj);
            float xm[6];
            load6(meas + 6 * (size_t)e, xm);
            loss += edge_residual(qi, ti, qj, tj, xm);
        }
    }

    #pragma unroll
    for (int off = 32; off > 0; off >>= 1)
        loss += __shfl_down(loss, off);

    __shared__ float sdata[4];
    const int lane = threadIdx.x & 63;
    const int wid = threadIdx.x >> 6;
    if (lane == 0) sdata[wid] = loss;
    __syncthreads();
    if (threadIdx.x == 0)
        partials[blockIdx.x] = (sdata[0] + sdata[1]) + (sdata[2] + sdata[3]);
}

// ---------- kernel 3: final reduce ----------
__global__ __launch_bounds__(256) void reduce_kernel(
    const float* __restrict__ partials, int n, float* __restrict__ out, float invE)
{
    float s = 0.0f;
    for (int i = threadIdx.x; i < n; i += 256) s += partials[i];
    #pragma unroll
    for (int off = 32; off > 0; off >>= 1) s += __shfl_down(s, off);
    __shared__ float sd[4];
    const int lane = threadIdx.x & 63;
    const int wid = threadIdx.x >> 6;
    if (lane == 0) sd[wid] = s;
    __syncthreads();
    if (threadIdx.x == 0) out[0] = ((sd[0] + sd[1]) + (sd[2] + sd[3])) * invE;
}

// ---------- fallback (ws too small): fused, atomic ----------
__global__ void zero_out_kernel(float* out) { out[0] = 0.0f; }

__global__ __launch_bounds__(256) void fused_kernel(
    const float* __restrict__ poses,
    const int* __restrict__ edges,
    const float* __restrict__ meas,
    float* __restrict__ out,
    int N, int E, float invE)
{
    const int e = blockIdx.x * blockDim.x + threadIdx.x;
    float loss = 0.0f;
    if (e < E) {
        const int i = edges[2 * e];
        const int j = edges[2 * e + 1];
        float xi_i[6], xi_j[6], xi_m[6];
        load6(poses + 6 * (size_t)i, xi_i);
        load6(poses + 6 * (size_t)j, xi_j);
        load6(meas + 6 * (size_t)e, xi_m);
        float qi[4], ti[3], qj[4], tj[3];
        exp_se3_quat(xi_i, qi, ti);
        exp_se3_quat(xi_j, qj, tj);
        loss = edge_residual(qi, ti, qj, tj, xi_m);
    }
    #pragma unroll
    for (int off = 32; off > 0; off >>= 1) loss += __shfl_down(loss, off);
    __shared__ float sdata[4];
    const int lane = threadIdx.x & 63;
    const int wid = threadIdx.x >> 6;
    if (lane == 0) sdata[wid] = loss;
    __syncthreads();
    if (threadIdx.x == 0)
        atomicAdd(out, ((sdata[0] + sdata[1]) + (sdata[2] + sdata[3])) * invE);
}

extern "C" void kernel_launch(void* const* d_in, const int* in_sizes, int n_in,
                              void* d_out, int out_size, void* d_ws, size_t ws_size,
                              hipStream_t stream) {
    const float* poses = (const float*)d_in[0];
    const int*   edges = (const int*)d_in[1];
    const float* meas  = (const float*)d_in[2];
    float* out = (float*)d_out;

    const int N = in_sizes[0] / 6;
    const int E = in_sizes[2] / 6;
    const float invE = 1.0f / (float)E;

    const int block = 256;
    const int nthreads = (E + 3) / 4;                 // 4 edges per thread
    const int grid_e = (nthreads + block - 1) / block;
    const size_t table_bytes = (size_t)N * 8 * sizeof(float);   // 32 B / pose
    const size_t need = table_bytes + (size_t)grid_e * sizeof(float);

    if (ws_size >= need) {
        float* table = (float*)d_ws;
        float* partials = (float*)((char*)d_ws + table_bytes);
        const int grid_n = (N + block - 1) / block;
        exp_poses_kernel<<<grid_n, block, 0, stream>>>(poses, table, N);
        edge_loss_kernel<<<grid_e, block, 0, stream>>>(table, edges, meas, partials, N, E);
        reduce_kernel<<<1, block, 0, stream>>>(partials, grid_e, out, invE);
    } else {
        zero_out_kernel<<<1, 1, 0, stream>>>(out);
        const int grid_f = (E + block - 1) / block;
        fused_kernel<<<grid_f, block, 0, stream>>>(poses, edges, meas, out, N, E, invE);
    }
}

// Round 6
// 54.741 us; speedup vs baseline: 1.4335x; 1.0632x over previous
//
#include <hip/hip_runtime.h>
#include <math.h>

#define SMALL_EPS 1e-8f

typedef float f4 __attribute__((ext_vector_type(4)));
typedef int   i4 __attribute__((ext_vector_type(4)));

__device__ __forceinline__ float frcp(float x) { return __builtin_amdgcn_rcpf(x); }
__device__ __forceinline__ float frsq(float x) { return __builtin_amdgcn_rsqf(x); }

// max abs err ~7e-5 rad (Abramowitz-Stegun 4.4.45)
__device__ __forceinline__ float fast_acos(float x) {
    float ax = fabsf(x);
    float r = sqrtf(fmaxf(1.0f - ax, 0.0f)) *
        (1.5707288f + ax * (-0.2121144f + ax * (0.0742610f + ax * (-0.0187293f))));
    return (x < 0.0f) ? (3.14159265358979f - r) : r;
}

// exp map to (unit quaternion, translation):  xi[6] -> q[4], t[3]
__device__ __forceinline__ void exp_se3_quat(const float xi[6], float q[4], float t[3]) {
    const float x = xi[0], y = xi[1], z = xi[2];
    const float t2 = x * x + y * y + z * z;
    const float t2s = fmaxf(t2, 1e-12f);
    const float rth = frsq(t2s);          // 1/sqrt
    const float th  = t2s * rth;          // sqrt
    const float rt2 = rth * rth;          // 1/t2s
    float sh, ch;
    __sincosf(0.5f * th, &sh, &ch);
    const bool small = t2 < SMALL_EPS;
    const float k = small ? 0.5f - t2 * (1.0f / 48.0f) : sh * rth;  // sin(th/2)/th
    q[0] = ch; q[1] = k * x; q[2] = k * y; q[3] = k * z;
    const float sin_th = 2.0f * sh * ch;
    const float cos_th = 1.0f - 2.0f * sh * sh;
    const float B = small ? 0.5f - t2 * (1.0f / 24.0f)            : (1.0f - cos_th) * rt2;
    const float C = small ? (1.0f / 6.0f) - t2 * (1.0f / 120.0f)  : (th - sin_th) * rt2 * rth;
    const float v0 = xi[3], v1 = xi[4], v2 = xi[5];
    const float c0 = y * v2 - z * v1;
    const float c1 = z * v0 - x * v2;
    const float c2 = x * v1 - y * v0;
    const float d0 = y * c2 - z * c1;
    const float d1 = z * c0 - x * c2;
    const float d2 = x * c1 - y * c0;
    t[0] = v0 + B * c0 + C * d0;
    t[1] = v1 + B * c1 + C * d1;
    t[2] = v2 + B * c2 + C * d2;
}

// o = conj(a) * b
__device__ __forceinline__ void qconj_mul(const float a[4], const float b[4], float o[4]) {
    o[0] = a[0] * b[0] + a[1] * b[1] + a[2] * b[2] + a[3] * b[3];
    o[1] = a[0] * b[1] - b[0] * a[1] - (a[2] * b[3] - a[3] * b[2]);
    o[2] = a[0] * b[2] - b[0] * a[2] - (a[3] * b[1] - a[1] * b[3]);
    o[3] = a[0] * b[3] - b[0] * a[3] - (a[1] * b[2] - a[2] * b[1]);
}

// o = R(q)^T v
__device__ __forceinline__ void qconj_rot(const float q[4], const float v[3], float o[3]) {
    const float ux = -q[1], uy = -q[2], uz = -q[3];
    const float tx = 2.0f * (uy * v[2] - uz * v[1]);
    const float ty = 2.0f * (uz * v[0] - ux * v[2]);
    const float tz = 2.0f * (ux * v[1] - uy * v[0]);
    o[0] = v[0] + q[0] * tx + (uy * tz - uz * ty);
    o[1] = v[1] + q[0] * ty + (uz * tx - ux * tz);
    o[2] = v[2] + q[0] * tz + (ux * ty - uy * tx);
}

// log map from (q, t) -> sum of squares of xi
__device__ __forceinline__ float log_se3_sq_quat(const float q[4], const float t[3]) {
    const float cth = fminf(fmaxf(2.0f * q[0] * q[0] - 1.0f, -1.0f), 1.0f);
    const float th = fast_acos(cth);
    const float t2 = th * th;
    const float t2s = fmaxf(t2, 1e-12f);
    const float rt2s = frcp(t2s);
    const bool small = t2 < SMALL_EPS;
    const float sth = sqrtf(fmaxf(1.0f - cth * cth, 0.0f));
    const float fac = small ? 0.5f + t2 * (1.0f / 12.0f) : 0.5f * th * frcp(sth);
    const float g = 4.0f * q[0] * fac;
    const float wx = g * q[1], wy = g * q[2], wz = g * q[3];
    const float A = small ? 1.0f : sth * frcp(th);
    const float B = small ? 0.5f : (1.0f - cth) * rt2s;
    const float coef = small ? (1.0f / 12.0f) + t2 * (1.0f / 720.0f)
                             : (1.0f - 0.5f * A * frcp(B)) * rt2s;
    const float c0 = wy * t[2] - wz * t[1];
    const float c1 = wz * t[0] - wx * t[2];
    const float c2 = wx * t[1] - wy * t[0];
    const float d0 = wy * c2 - wz * c1;
    const float d1 = wz * c0 - wx * c2;
    const float d2 = wx * c1 - wy * c0;
    const float vx = t[0] - 0.5f * c0 + coef * d0;
    const float vy = t[1] - 0.5f * c1 + coef * d1;
    const float vz = t[2] - 0.5f * c2 + coef * d2;
    return wx * wx + wy * wy + wz * wz + vx * vx + vy * vy + vz * vz;
}

__device__ __forceinline__ void load6(const float* __restrict__ p, float xi[6]) {
    const float2* p2 = reinterpret_cast<const float2*>(p);
    float2 a = p2[0], b = p2[1], c = p2[2];
    xi[0] = a.x; xi[1] = a.y; xi[2] = b.x; xi[3] = b.y; xi[4] = c.x; xi[5] = c.y;
}

// residual for one edge given pre-loaded poses (as quat+t) and measurement xi
__device__ __forceinline__ float edge_residual(
    const float qi[4], const float ti[3],
    const float qj[4], const float tj[3],
    const float xm[6])
{
    float qm[4], tm[3];
    exp_se3_quat(xm, qm, tm);
    float qc[4], tc[3];
    const float dvec[3] = { tj[0] - ti[0], tj[1] - ti[1], tj[2] - ti[2] };
    qconj_mul(qi, qj, qc);
    qconj_rot(qi, dvec, tc);
    float qr[4], tr[3];
    const float evec[3] = { tc[0] - tm[0], tc[1] - tm[1], tc[2] - tm[2] };
    qconj_mul(qm, qc, qr);
    qconj_rot(qm, evec, tr);
    return log_se3_sq_quat(qr, tr);
}

// ---------- kernel 1: exp all poses into 32B (quat+t) records ----------
__global__ __launch_bounds__(256) void exp_poses_kernel(
    const float* __restrict__ poses, float* __restrict__ table, int N)
{
    const int i = blockIdx.x * blockDim.x + threadIdx.x;
    if (i >= N) return;
    float xi[6];
    load6(poses + 6 * (size_t)i, xi);
    float q[4], t[3];
    exp_se3_quat(xi, q, t);
    f4* slot = reinterpret_cast<f4*>(table + 8 * (size_t)i);
    slot[0] = (f4){q[0], q[1], q[2], q[3]};
    slot[1] = (f4){t[0], t[1], t[2], 0.0f};
}

__device__ __forceinline__ void load_pose(const float* __restrict__ table, int i,
                                          float q[4], float t[3])
{
    const f4* slot = reinterpret_cast<const f4*>(table + 8 * (size_t)i);
    const f4 a = slot[0], b = slot[1];
    q[0] = a.x; q[1] = a.y; q[2] = a.z; q[3] = a.w;
    t[0] = b.x; t[1] = b.y; t[2] = b.z;
}

// ---------- kernel 2: per-edge residual, 2 edges/thread, block partials ----------
__global__ __launch_bounds__(256) void edge_loss_kernel(
    const float* __restrict__ table,
    const int* __restrict__ edges,
    const float* __restrict__ meas,
    float* __restrict__ partials,
    int N, int E)
{
    const int t = blockIdx.x * blockDim.x + threadIdx.x;
    const long e0 = 2L * t;
    float loss = 0.0f;

    if (e0 + 1 < E) {
        // one int4 = both edge pairs (16 B, coalesced)
        const i4 ed = *reinterpret_cast<const i4*>(edges + 4 * (size_t)t);

        // 4 independent pose gathers (2x16 B each), issued before compute
        float qi0[4], ti0[3], qj0[4], tj0[3];
        float qi1[4], ti1[3], qj1[4], tj1[3];
        load_pose(table, ed.x, qi0, ti0);
        load_pose(table, ed.y, qj0, tj0);
        load_pose(table, ed.z, qi1, ti1);
        load_pose(table, ed.w, qj1, tj1);

        // both measurements: 3x float4 (48 B, 16B-aligned, coalesced)
        const f4* mp = reinterpret_cast<const f4*>(meas + 12 * (size_t)t);
        const f4 m0 = mp[0];
        const f4 m1 = mp[1];
        const f4 m2 = mp[2];
        const float xmA[6] = { m0.x, m0.y, m0.z, m0.w, m1.x, m1.y };
        const float xmB[6] = { m1.z, m1.w, m2.x, m2.y, m2.z, m2.w };

        loss = edge_residual(qi0, ti0, qj0, tj0, xmA)
             + edge_residual(qi1, ti1, qj1, tj1, xmB);
    } else if (e0 < E) {
        // tail: single edge
        const int i = edges[2 * e0];
        const int j = edges[2 * e0 + 1];
        float qi[4], ti[3], qj[4], tj[3];
        load_pose(table, i, qi, ti);
        load_pose(table, j, qj, tj);
        float xm[6];
        load6(meas + 6 * (size_t)e0, xm);
        loss = edge_residual(qi, ti, qj, tj, xm);
    }

    #pragma unroll
    for (int off = 32; off > 0; off >>= 1)
        loss += __shfl_down(loss, off);

    __shared__ float sdata[4];
    const int lane = threadIdx.x & 63;
    const int wid = threadIdx.x >> 6;
    if (lane == 0) sdata[wid] = loss;
    __syncthreads();
    if (threadIdx.x == 0)
        partials[blockIdx.x] = (sdata[0] + sdata[1]) + (sdata[2] + sdata[3]);
}

// ---------- kernel 3: final reduce ----------
__global__ __launch_bounds__(256) void reduce_kernel(
    const float* __restrict__ partials, int n, float* __restrict__ out, float invE)
{
    float s = 0.0f;
    for (int i = threadIdx.x; i < n; i += 256) s += partials[i];
    #pragma unroll
    for (int off = 32; off > 0; off >>= 1) s += __shfl_down(s, off);
    __shared__ float sd[4];
    const int lane = threadIdx.x & 63;
    const int wid = threadIdx.x >> 6;
    if (lane == 0) sd[wid] = s;
    __syncthreads();
    if (threadIdx.x == 0) out[0] = ((sd[0] + sd[1]) + (sd[2] + sd[3])) * invE;
}

// ---------- fallback (ws too small): fused, atomic ----------
__global__ void zero_out_kernel(float* out) { out[0] = 0.0f; }

__global__ __launch_bounds__(256) void fused_kernel(
    const float* __restrict__ poses,
    const int* __restrict__ edges,
    const float* __restrict__ meas,
    float* __restrict__ out,
    int N, int E, float invE)
{
    const int e = blockIdx.x * blockDim.x + threadIdx.x;
    float loss = 0.0f;
    if (e < E) {
        const int i = edges[2 * e];
        const int j = edges[2 * e + 1];
        float xi_i[6], xi_j[6], xi_m[6];
        load6(poses + 6 * (size_t)i, xi_i);
        load6(poses + 6 * (size_t)j, xi_j);
        load6(meas + 6 * (size_t)e, xi_m);
        float qi[4], ti[3], qj[4], tj[3];
        exp_se3_quat(xi_i, qi, ti);
        exp_se3_quat(xi_j, qj, tj);
        loss = edge_residual(qi, ti, qj, tj, xi_m);
    }
    #pragma unroll
    for (int off = 32; off > 0; off >>= 1) loss += __shfl_down(loss, off);
    __shared__ float sdata[4];
    const int lane = threadIdx.x & 63;
    const int wid = threadIdx.x >> 6;
    if (lane == 0) sdata[wid] = loss;
    __syncthreads();
    if (threadIdx.x == 0)
        atomicAdd(out, ((sdata[0] + sdata[1]) + (sdata[2] + sdata[3])) * invE);
}

extern "C" void kernel_launch(void* const* d_in, const int* in_sizes, int n_in,
                              void* d_out, int out_size, void* d_ws, size_t ws_size,
                              hipStream_t stream) {
    const float* poses = (const float*)d_in[0];
    const int*   edges = (const int*)d_in[1];
    const float* meas  = (const float*)d_in[2];
    float* out = (float*)d_out;

    const int N = in_sizes[0] / 6;
    const int E = in_sizes[2] / 6;
    const float invE = 1.0f / (float)E;

    const int block = 256;
    const int nthreads = (E + 1) / 2;                 // 2 edges per thread
    const int grid_e = (nthreads + block - 1) / block;
    const size_t table_bytes = (size_t)N * 8 * sizeof(float);   // 32 B / pose
    const size_t need = table_bytes + (size_t)grid_e * sizeof(float);

    if (ws_size >= need) {
        float* table = (float*)d_ws;
        float* partials = (float*)((char*)d_ws + table_bytes);
        const int grid_n = (N + block - 1) / block;
        exp_poses_kernel<<<grid_n, block, 0, stream>>>(poses, table, N);
        edge_loss_kernel<<<grid_e, block, 0, stream>>>(table, edges, meas, partials, N, E);
        reduce_kernel<<<1, block, 0, stream>>>(partials, grid_e, out, invE);
    } else {
        zero_out_kernel<<<1, 1, 0, stream>>>(out);
        const int grid_f = (E + block - 1) / block;
        fused_kernel<<<grid_f, block, 0, stream>>>(poses, edges, meas, out, N, E, invE);
    }
}

// Round 7
// 39.988 us; speedup vs baseline: 1.9624x; 1.3689x over previous
//
#include <hip/hip_runtime.h>
#include <math.h>

#define SMALL_EPS 1e-8f

typedef float     f4 __attribute__((ext_vector_type(4)));
typedef int       i4 __attribute__((ext_vector_type(4)));
typedef _Float16  h8 __attribute__((ext_vector_type(8)));   // 16 B pose record

__device__ __forceinline__ float frcp(float x) { return __builtin_amdgcn_rcpf(x); }
__device__ __forceinline__ float frsq(float x) { return __builtin_amdgcn_rsqf(x); }

// max abs err ~7e-5 rad (Abramowitz-Stegun 4.4.45)
__device__ __forceinline__ float fast_acos(float x) {
    float ax = fabsf(x);
    float r = sqrtf(fmaxf(1.0f - ax, 0.0f)) *
        (1.5707288f + ax * (-0.2121144f + ax * (0.0742610f + ax * (-0.0187293f))));
    return (x < 0.0f) ? (3.14159265358979f - r) : r;
}

// exp map to (unit quaternion, translation):  xi[6] -> q[4], t[3]
__device__ __forceinline__ void exp_se3_quat(const float xi[6], float q[4], float t[3]) {
    const float x = xi[0], y = xi[1], z = xi[2];
    const float t2 = x * x + y * y + z * z;
    const float t2s = fmaxf(t2, 1e-12f);
    const float rth = frsq(t2s);          // 1/sqrt
    const float th  = t2s * rth;          // sqrt
    const float rt2 = rth * rth;          // 1/t2s
    float sh, ch;
    __sincosf(0.5f * th, &sh, &ch);
    const bool small = t2 < SMALL_EPS;
    const float k = small ? 0.5f - t2 * (1.0f / 48.0f) : sh * rth;  // sin(th/2)/th
    q[0] = ch; q[1] = k * x; q[2] = k * y; q[3] = k * z;
    const float sin_th = 2.0f * sh * ch;
    const float cos_th = 1.0f - 2.0f * sh * sh;
    const float B = small ? 0.5f - t2 * (1.0f / 24.0f)            : (1.0f - cos_th) * rt2;
    const float C = small ? (1.0f / 6.0f) - t2 * (1.0f / 120.0f)  : (th - sin_th) * rt2 * rth;
    const float v0 = xi[3], v1 = xi[4], v2 = xi[5];
    const float c0 = y * v2 - z * v1;
    const float c1 = z * v0 - x * v2;
    const float c2 = x * v1 - y * v0;
    const float d0 = y * c2 - z * c1;
    const float d1 = z * c0 - x * c2;
    const float d2 = x * c1 - y * c0;
    t[0] = v0 + B * c0 + C * d0;
    t[1] = v1 + B * c1 + C * d1;
    t[2] = v2 + B * c2 + C * d2;
}

// o = conj(a) * b
__device__ __forceinline__ void qconj_mul(const float a[4], const float b[4], float o[4]) {
    o[0] = a[0] * b[0] + a[1] * b[1] + a[2] * b[2] + a[3] * b[3];
    o[1] = a[0] * b[1] - b[0] * a[1] - (a[2] * b[3] - a[3] * b[2]);
    o[2] = a[0] * b[2] - b[0] * a[2] - (a[3] * b[1] - a[1] * b[3]);
    o[3] = a[0] * b[3] - b[0] * a[3] - (a[1] * b[2] - a[2] * b[1]);
}

// o = R(q)^T v
__device__ __forceinline__ void qconj_rot(const float q[4], const float v[3], float o[3]) {
    const float ux = -q[1], uy = -q[2], uz = -q[3];
    const float tx = 2.0f * (uy * v[2] - uz * v[1]);
    const float ty = 2.0f * (uz * v[0] - ux * v[2]);
    const float tz = 2.0f * (ux * v[1] - uy * v[0]);
    o[0] = v[0] + q[0] * tx + (uy * tz - uz * ty);
    o[1] = v[1] + q[0] * ty + (uz * tx - ux * tz);
    o[2] = v[2] + q[0] * tz + (ux * ty - uy * tx);
}

// log map from (q, t) -> sum of squares of xi
__device__ __forceinline__ float log_se3_sq_quat(const float q[4], const float t[3]) {
    const float cth = fminf(fmaxf(2.0f * q[0] * q[0] - 1.0f, -1.0f), 1.0f);
    const float th = fast_acos(cth);
    const float t2 = th * th;
    const float t2s = fmaxf(t2, 1e-12f);
    const float rt2s = frcp(t2s);
    const bool small = t2 < SMALL_EPS;
    const float sth = sqrtf(fmaxf(1.0f - cth * cth, 0.0f));
    const float fac = small ? 0.5f + t2 * (1.0f / 12.0f) : 0.5f * th * frcp(sth);
    const float g = 4.0f * q[0] * fac;
    const float wx = g * q[1], wy = g * q[2], wz = g * q[3];
    const float A = small ? 1.0f : sth * frcp(th);
    const float B = small ? 0.5f : (1.0f - cth) * rt2s;
    const float coef = small ? (1.0f / 12.0f) + t2 * (1.0f / 720.0f)
                             : (1.0f - 0.5f * A * frcp(B)) * rt2s;
    const float c0 = wy * t[2] - wz * t[1];
    const float c1 = wz * t[0] - wx * t[2];
    const float c2 = wx * t[1] - wy * t[0];
    const float d0 = wy * c2 - wz * c1;
    const float d1 = wz * c0 - wx * c2;
    const float d2 = wx * c1 - wy * c0;
    const float vx = t[0] - 0.5f * c0 + coef * d0;
    const float vy = t[1] - 0.5f * c1 + coef * d1;
    const float vz = t[2] - 0.5f * c2 + coef * d2;
    return wx * wx + wy * wy + wz * wz + vx * vx + vy * vy + vz * vz;
}

__device__ __forceinline__ void load6(const float* __restrict__ p, float xi[6]) {
    const float2* p2 = reinterpret_cast<const float2*>(p);
    float2 a = p2[0], b = p2[1], c = p2[2];
    xi[0] = a.x; xi[1] = a.y; xi[2] = b.x; xi[3] = b.y; xi[4] = c.x; xi[5] = c.y;
}

__device__ __forceinline__ void unpack_pose(const h8 rec, float q[4], float t[3]) {
    q[0] = (float)rec[0]; q[1] = (float)rec[1]; q[2] = (float)rec[2]; q[3] = (float)rec[3];
    t[0] = (float)rec[4]; t[1] = (float)rec[5]; t[2] = (float)rec[6];
}

// residual given both poses (quat+t) and precomputed measurement (qm,tm)
__device__ __forceinline__ float edge_residual_pre(
    const float qi[4], const float ti[3],
    const float qj[4], const float tj[3],
    const float qm[4], const float tm[3])
{
    float qc[4], tc[3];
    const float dvec[3] = { tj[0] - ti[0], tj[1] - ti[1], tj[2] - ti[2] };
    qconj_mul(qi, qj, qc);
    qconj_rot(qi, dvec, tc);
    float qr[4], tr[3];
    const float evec[3] = { tc[0] - tm[0], tc[1] - tm[1], tc[2] - tm[2] };
    qconj_mul(qm, qc, qr);
    qconj_rot(qm, evec, tr);
    return log_se3_sq_quat(qr, tr);
}

// ---------- kernel 1: exp all poses into 16B f16 (quat+t) records ----------
__global__ __launch_bounds__(256) void exp_poses_kernel(
    const float* __restrict__ poses, h8* __restrict__ table, int N)
{
    const int i = blockIdx.x * blockDim.x + threadIdx.x;
    if (i >= N) return;
    float xi[6];
    load6(poses + 6 * (size_t)i, xi);
    float q[4], t[3];
    exp_se3_quat(xi, q, t);
    h8 rec;
    rec[0] = (_Float16)q[0]; rec[1] = (_Float16)q[1];
    rec[2] = (_Float16)q[2]; rec[3] = (_Float16)q[3];
    rec[4] = (_Float16)t[0]; rec[5] = (_Float16)t[1];
    rec[6] = (_Float16)t[2]; rec[7] = (_Float16)0.0f;
    table[i] = rec;
}

// ---------- kernel 2: per-edge residual, 2 edges/thread, block partials ----------
__global__ __launch_bounds__(256) void edge_loss_kernel(
    const h8* __restrict__ table,
    const int* __restrict__ edges,
    const float* __restrict__ meas,
    float* __restrict__ partials,
    int N, int E)
{
    const int t = blockIdx.x * blockDim.x + threadIdx.x;
    const long e0 = 2L * t;
    float loss = 0.0f;

    if (e0 + 1 < E) {
        // independent streaming loads first: edge int4 + 3x meas float4
        const i4 ed = *reinterpret_cast<const i4*>(edges + 4 * (size_t)t);
        const f4* mp = reinterpret_cast<const f4*>(meas + 12 * (size_t)t);
        const f4 m0 = mp[0];
        const f4 m1 = mp[1];
        const f4 m2 = mp[2];

        // 4 pose gathers, ONE 16 B request each (issued as soon as ed lands)
        const h8 p0 = table[ed.x];
        const h8 p1 = table[ed.y];
        const h8 p2 = table[ed.z];
        const h8 p3 = table[ed.w];

        // measurement exp maps overlap the gather latency (no dependence)
        const float xmA[6] = { m0.x, m0.y, m0.z, m0.w, m1.x, m1.y };
        const float xmB[6] = { m1.z, m1.w, m2.x, m2.y, m2.z, m2.w };
        float qmA[4], tmA[3], qmB[4], tmB[3];
        exp_se3_quat(xmA, qmA, tmA);
        exp_se3_quat(xmB, qmB, tmB);

        float qi0[4], ti0[3], qj0[4], tj0[3];
        float qi1[4], ti1[3], qj1[4], tj1[3];
        unpack_pose(p0, qi0, ti0);
        unpack_pose(p1, qj0, tj0);
        unpack_pose(p2, qi1, ti1);
        unpack_pose(p3, qj1, tj1);

        loss = edge_residual_pre(qi0, ti0, qj0, tj0, qmA, tmA)
             + edge_residual_pre(qi1, ti1, qj1, tj1, qmB, tmB);
    } else if (e0 < E) {
        // tail: single edge
        const int i = edges[2 * e0];
        const int j = edges[2 * e0 + 1];
        float xm[6];
        load6(meas + 6 * (size_t)e0, xm);
        float qm[4], tm[3];
        exp_se3_quat(xm, qm, tm);
        float qi[4], ti[3], qj[4], tj[3];
        unpack_pose(table[i], qi, ti);
        unpack_pose(table[j], qj, tj);
        loss = edge_residual_pre(qi, ti, qj, tj, qm, tm);
    }

    #pragma unroll
    for (int off = 32; off > 0; off >>= 1)
        loss += __shfl_down(loss, off);

    __shared__ float sdata[4];
    const int lane = threadIdx.x & 63;
    const int wid = threadIdx.x >> 6;
    if (lane == 0) sdata[wid] = loss;
    __syncthreads();
    if (threadIdx.x == 0)
        partials[blockIdx.x] = (sdata[0] + sdata[1]) + (sdata[2] + sdata[3]);
}

// ---------- kernel 3: final reduce ----------
__global__ __launch_bounds__(256) void reduce_kernel(
    const float* __restrict__ partials, int n, float* __restrict__ out, float invE)
{
    float s = 0.0f;
    for (int i = threadIdx.x; i < n; i += 256) s += partials[i];
    #pragma unroll
    for (int off = 32; off > 0; off >>= 1) s += __shfl_down(s, off);
    __shared__ float sd[4];
    const int lane = threadIdx.x & 63;
    const int wid = threadIdx.x >> 6;
    if (lane == 0) sd[wid] = s;
    __syncthreads();
    if (threadIdx.x == 0) out[0] = ((sd[0] + sd[1]) + (sd[2] + sd[3])) * invE;
}

// ---------- fallback (ws too small): fused, atomic, full f32 ----------
__global__ void zero_out_kernel(float* out) { out[0] = 0.0f; }

__global__ __launch_bounds__(256) void fused_kernel(
    const float* __restrict__ poses,
    const int* __restrict__ edges,
    const float* __restrict__ meas,
    float* __restrict__ out,
    int N, int E, float invE)
{
    const int e = blockIdx.x * blockDim.x + threadIdx.x;
    float loss = 0.0f;
    if (e < E) {
        const int i = edges[2 * e];
        const int j = edges[2 * e + 1];
        float xi_i[6], xi_j[6], xi_m[6];
        load6(poses + 6 * (size_t)i, xi_i);
        load6(poses + 6 * (size_t)j, xi_j);
        load6(meas + 6 * (size_t)e, xi_m);
        float qi[4], ti[3], qj[4], tj[3], qm[4], tm[3];
        exp_se3_quat(xi_i, qi, ti);
        exp_se3_quat(xi_j, qj, tj);
        exp_se3_quat(xi_m, qm, tm);
        loss = edge_residual_pre(qi, ti, qj, tj, qm, tm);
    }
    #pragma unroll
    for (int off = 32; off > 0; off >>= 1) loss += __shfl_down(loss, off);
    __shared__ float sdata[4];
    const int lane = threadIdx.x & 63;
    const int wid = threadIdx.x >> 6;
    if (lane == 0) sdata[wid] = loss;
    __syncthreads();
    if (threadIdx.x == 0)
        atomicAdd(out, ((sdata[0] + sdata[1]) + (sdata[2] + sdata[3])) * invE);
}

extern "C" void kernel_launch(void* const* d_in, const int* in_sizes, int n_in,
                              void* d_out, int out_size, void* d_ws, size_t ws_size,
                              hipStream_t stream) {
    const float* poses = (const float*)d_in[0];
    const int*   edges = (const int*)d_in[1];
    const float* meas  = (const float*)d_in[2];
    float* out = (float*)d_out;

    const int N = in_sizes[0] / 6;
    const int E = in_sizes[2] / 6;
    const float invE = 1.0f / (float)E;

    const int block = 256;
    const int nthreads = (E + 1) / 2;                 // 2 edges per thread
    const int grid_e = (nthreads + block - 1) / block;
    const size_t table_bytes = (size_t)N * 16;        // 16 B / pose (8 x f16)
    const size_t need = table_bytes + (size_t)grid_e * sizeof(float);

    if (ws_size >= need) {
        h8* table = (h8*)d_ws;
        float* partials = (float*)((char*)d_ws + table_bytes);
        const int grid_n = (N + block - 1) / block;
        exp_poses_kernel<<<grid_n, block, 0, stream>>>(poses, table, N);
        edge_loss_kernel<<<grid_e, block, 0, stream>>>(table, edges, meas, partials, N, E);
        reduce_kernel<<<1, block, 0, stream>>>(partials, grid_e, out, invE);
    } else {
        zero_out_kernel<<<1, 1, 0, stream>>>(out);
        const int grid_f = (E + block - 1) / block;
        fused_kernel<<<grid_f, block, 0, stream>>>(poses, edges, meas, out, N, E, invE);
    }
}